// Round 7
// baseline (684.848 us; speedup 1.0000x reference)
//
#include <hip/hip_runtime.h>
#include <math.h>

// Problem constants (from reference setup_inputs)
constexpr int Bq = 32;
constexpr int Tq = 8192;
constexpr int Dq = 8;
constexpr int Qq = 8;
constexpr int Kq = 1024;
constexpr int NTOK = Bq * Tq;                         // 262144 tokens
constexpr float LOSS_SCALE = 0.25f / (float)(Bq * Tq * Dq);

typedef float v2f __attribute__((ext_vector_type(2)));

// Round 7: 8 tokens/lane x 8 k-slices + packed-f32 (v_pk_fma_f32) dots.
// R6 analysis: VALU exec ~852K cy/SIMD, LDS ~977K cy/CU, neither saturated at
// 1.57M cy. Tk=8 halves LDS (3 ds_reads feed 8 tokens; ~488K cy/CU) and
// pk-f32 halves dot-instruction count (~560K cy/SIMD). 157.3 TF fp32 spec IS
// the packed rate. pk ops are per-component IEEE RN -> d2 bits identical to
// all passing rounds (seq mul/fma dot, d2=fmaf(dot,-2,rn+cn), first-min).
// Skew: slice stride 1028 floats = 4 mod 32 -> 8 slices on disjoint 4-bank
// groups; 16B alignment kept (skew step = 4 floats).
// Merge: 3-stage shfl_xor(8,16,32), lexicographic (d2,k) = np first-min.
__global__ __launch_bounds__(256, 4)
void rvq_main(const float* __restrict__ x,
              const float* __restrict__ codebooks,
              const float* __restrict__ post_scale,
              const float* __restrict__ post_bias,
              const float* __restrict__ conv_w,
              const float* __restrict__ conv_b,
              float* __restrict__ out)
{
    __shared__ __align__(16) float s_cb[8224];      // skewed codebook (32.1KB)
    __shared__ float s_cn[1056];                    // skewed norms

    const int tid   = threadIdx.x;
    const int lane  = tid & 63;
    const int wave  = tid >> 6;                    // 0..3
    const int slice = lane >> 3;                   // 0..7 -> k eighth
    const int sub   = lane & 7;                    // 0..7 -> token subgroup
    const int kbase = slice << 7;                  // 0,128,...,896
    const int tbase = blockIdx.x * 256 + wave * 64 + sub;  // + 8*j, j=0..7

    // residuals: 8 tokens per lane, packed in pairs: rp[p][d] = {tok 2p, 2p+1}
    v2f rp[4][Dq];
#pragma unroll
    for (int p = 0; p < 4; ++p) {
        const float4* xp0 = reinterpret_cast<const float4*>(
            x + (size_t)(tbase + 8 * (2 * p)) * Dq);
        const float4* xp1 = reinterpret_cast<const float4*>(
            x + (size_t)(tbase + 8 * (2 * p + 1)) * Dq);
        float4 a0 = xp0[0], b0 = xp0[1], a1 = xp1[0], b1 = xp1[1];
        rp[p][0] = (v2f){a0.x, a1.x}; rp[p][1] = (v2f){a0.y, a1.y};
        rp[p][2] = (v2f){a0.z, a1.z}; rp[p][3] = (v2f){a0.w, a1.w};
        rp[p][4] = (v2f){b0.x, b1.x}; rp[p][5] = (v2f){b0.y, b1.y};
        rp[p][6] = (v2f){b0.z, b1.z}; rp[p][7] = (v2f){b0.w, b1.w};
    }

    // qsum only for the owned token (j == slice)
    float qso[Dq];
#pragma unroll
    for (int d = 0; d < Dq; ++d) qso[d] = 0.0f;
    float lossacc = 0.0f;

    float* out_quant = out;                               // [B*T*D]
    float* out_loss  = out + (size_t)NTOK * Dq;           // [1]
    float* out_codes = out_loss + 1;                      // [Q*B*T] as float

    for (int q = 0; q < Qq; ++q) {
        // ---- stage codebook q into LDS, skewed: float4 idx i -> i + (i>>8) ----
        {
            const float4* src = reinterpret_cast<const float4*>(
                codebooks + (size_t)q * Kq * Dq);
            float4* dst = reinterpret_cast<float4*>(s_cb);
#pragma unroll
            for (int it = 0; it < 8; ++it) {
                int i = tid + it * 256;
                dst[i + (i >> 8)] = src[i];
            }
        }
        __syncthreads();

        // ---- per-codeword squared norms (np order), skewed store ----
#pragma unroll
        for (int it = 0; it < 4; ++it) {
            int g = tid + it * 256;
            const float* c = s_cb + g * Dq + ((g >> 7) << 2);
            float n = __fmul_rn(c[0], c[0]);
#pragma unroll
            for (int d = 1; d < Dq; ++d)
                n = __fadd_rn(n, __fmul_rn(c[d], c[d]));
            s_cn[g + ((g >> 7) << 2)] = n;
        }
        __syncthreads();

        // ---- residual norms (np order), packed: same bits per component ----
        v2f rnp[4];
#pragma unroll
        for (int p = 0; p < 4; ++p) {
            v2f n = rp[p][0] * rp[p][0];               // pk_mul = 2x __fmul_rn
#pragma unroll
            for (int d = 1; d < Dq; ++d)
                n = n + rp[p][d] * rp[p][d];           // pk_add(pk_mul)
            rnp[p] = n;
        }

        // ---- argmin over this slice's 128 codewords, 8 tokens per read ----
        float best[8];
        int   bk[8];
#pragma unroll
        for (int j = 0; j < 8; ++j) { best[j] = __builtin_inff(); bk[j] = kbase; }

        const float4* cb4 = reinterpret_cast<const float4*>(s_cb) + 257 * slice;
        const float*  cnp = s_cn + 132 * slice;
#pragma unroll 2
        for (int k = 0; k < Kq / 8; ++k) {
            float4 ca = cb4[2 * k];
            float4 cc = cb4[2 * k + 1];
            float cn = cnp[k];
            int cand = kbase + k;
            v2f cnv = (v2f){cn, cn};
#pragma unroll
            for (int p = 0; p < 4; ++p) {
                v2f dot = rp[p][0] * (v2f){ca.x, ca.x};        // pk_mul
                dot = __builtin_elementwise_fma(rp[p][1], (v2f){ca.y, ca.y}, dot);
                dot = __builtin_elementwise_fma(rp[p][2], (v2f){ca.z, ca.z}, dot);
                dot = __builtin_elementwise_fma(rp[p][3], (v2f){ca.w, ca.w}, dot);
                dot = __builtin_elementwise_fma(rp[p][4], (v2f){cc.x, cc.x}, dot);
                dot = __builtin_elementwise_fma(rp[p][5], (v2f){cc.y, cc.y}, dot);
                dot = __builtin_elementwise_fma(rp[p][6], (v2f){cc.z, cc.z}, dot);
                dot = __builtin_elementwise_fma(rp[p][7], (v2f){cc.w, cc.w}, dot);
                v2f d2 = __builtin_elementwise_fma(
                    dot, (v2f){-2.0f, -2.0f}, rnp[p] + cnv);
                float d20 = d2[0], d21 = d2[1];
                if (d20 < best[2*p])   { best[2*p]   = d20; bk[2*p]   = cand; }
                if (d21 < best[2*p+1]) { best[2*p+1] = d21; bk[2*p+1] = cand; }
            }
        }

        // ---- merge 8 slices: lexicographic (d2, k) min == np first-min ----
        int own_bk = 0;
#pragma unroll
        for (int j = 0; j < 8; ++j) {
            float b = best[j]; int k = bk[j];
#pragma unroll
            for (int m = 8; m <= 32; m <<= 1) {
                float ob = __shfl_xor(b, m, 64);
                int   ok = __shfl_xor(k, m, 64);
                if (ob < b || (ob == b && ok < k)) { b = ob; k = ok; }
            }
            bk[j] = k;
            if (j == slice) own_bk = k;
        }

        const float sc = post_scale[q];
        const float bi = post_bias[q];

        // codes: each lane writes its owned token -> wave-contiguous 64 tokens
        out_codes[(size_t)q * NTOK + tbase + 8 * slice] = (float)own_bk;

        // ---- update residuals (all 8 tokens); qsum/loss for owned only ----
#pragma unroll
        for (int j = 0; j < 8; ++j) {
            int kj = bk[j];
            const float* cc = s_cb + kj * Dq + ((kj >> 7) << 2);
            const int p = j >> 1, h = j & 1;
#pragma unroll
            for (int d = 0; d < Dq; ++d) {
                float e = cc[d];
                float rd = rp[p][d][h];
                float est = __fadd_rn(rd, __fsub_rn(e, rd));
                if (j == slice)
                    qso[d] = __fadd_rn(__fadd_rn(qso[d], __fmul_rn(est, sc)), bi);
                float nr = __fsub_rn(rd, e);
                float df = __fsub_rn(nr, e);
                if (j == slice) lossacc = fmaf(df, df, lossacc);
                rp[p][d][h] = nr;
            }
        }
        __syncthreads();   // before next q overwrites s_cb
    }

    // ---- 1x1 conv epilogue: owned token only -> coalesced wave store ----
    {
        float o[Dq];
#pragma unroll
        for (int e = 0; e < Dq; ++e) {
            float acc = __fmul_rn(qso[0], conv_w[e * Dq + 0]);
#pragma unroll
            for (int d = 1; d < Dq; ++d)
                acc = fmaf(qso[d], conv_w[e * Dq + d], acc);
            o[e] = __fadd_rn(acc, conv_b[e]);
        }
        float4* op = reinterpret_cast<float4*>(
            out_quant + (size_t)(tbase + 8 * slice) * Dq);
        op[0] = make_float4(o[0], o[1], o[2], o[3]);
        op[1] = make_float4(o[4], o[5], o[6], o[7]);
    }

    // ---- loss reduction: each token counted once (owner lane) ----
    float v = lossacc;
#pragma unroll
    for (int off = 32; off >= 1; off >>= 1)
        v += __shfl_xor(v, off, 64);
    if (lane == 0)
        atomicAdd(out_loss, v * LOSS_SCALE);
}

extern "C" void kernel_launch(void* const* d_in, const int* in_sizes, int n_in,
                              void* d_out, int out_size, void* d_ws, size_t ws_size,
                              hipStream_t stream) {
    const float* x     = (const float*)d_in[0];
    const float* cb    = (const float*)d_in[1];
    const float* ps    = (const float*)d_in[2];
    const float* pb    = (const float*)d_in[3];
    const float* cw    = (const float*)d_in[4];
    const float* cbias = (const float*)d_in[5];
    float* out = (float*)d_out;

    // zero the loss accumulator slot (d_out is poisoned before every call)
    hipMemsetAsync(out + (size_t)NTOK * Dq, 0, sizeof(float), stream);

    rvq_main<<<dim3(NTOK / 256), dim3(256), 0, stream>>>(
        x, cb, ps, pb, cw, cbias, out);
}

// Round 8
// 647.886 us; speedup vs baseline: 1.0571x; 1.0571x over previous
//
#include <hip/hip_runtime.h>
#include <math.h>

// Problem constants (from reference setup_inputs)
constexpr int Bq = 32;
constexpr int Tq = 8192;
constexpr int Dq = 8;
constexpr int Qq = 8;
constexpr int Kq = 1024;
constexpr int NTOK = Bq * Tq;                         // 262144 tokens
constexpr float LOSS_SCALE = 0.25f / (float)(Bq * Tq * Dq);

typedef float v2f __attribute__((ext_vector_type(2)));

// Round 8: R6 structure (4 tokens/lane x 4 k-slices, skewed LDS, 60 VGPR,
// no spill) + packed-f32 dots (v_pk_fma_f32). R7 showed Tk=8 spills to
// scratch (+45 MB HBM traffic); Tk=4's state (32 regs of residuals) fits.
// pk ops are per-component IEEE RN -> d2 bits identical to all passing
// rounds (seq mul/fma dot, d2=fmaf(dot,-2,rn+cn), strict '<' first-min).
// Expected: VALU exec ~852K -> ~620K cy/SIMD; LDS floor ~983K cy/CU binds.
__global__ __launch_bounds__(256, 4)
void rvq_main(const float* __restrict__ x,
              const float* __restrict__ codebooks,
              const float* __restrict__ post_scale,
              const float* __restrict__ post_bias,
              const float* __restrict__ conv_w,
              const float* __restrict__ conv_b,
              float* __restrict__ out)
{
    __shared__ __align__(16) float s_cb[Kq * Dq + 32];  // skewed codebook
    __shared__ float s_cn[Kq + 32];                     // skewed norms

    const int tid   = threadIdx.x;
    const int lane  = tid & 63;
    const int wave  = tid >> 6;                    // 0..3
    const int slice = lane >> 4;                   // 0..3 -> k quarter
    const int sub   = lane & 15;                   // 0..15 -> token group
    const int kbase = slice << 8;                  // 0,256,512,768
    const int tbase = blockIdx.x * 256 + wave * 64 + sub;  // + 16*j, j=0..3

    // residuals: 4 tokens/lane packed in pairs: rp[p][d] = {tok 2p, tok 2p+1}
    v2f rp[2][Dq];
#pragma unroll
    for (int p = 0; p < 2; ++p) {
        const float4* xp0 = reinterpret_cast<const float4*>(
            x + (size_t)(tbase + 16 * (2 * p)) * Dq);
        const float4* xp1 = reinterpret_cast<const float4*>(
            x + (size_t)(tbase + 16 * (2 * p + 1)) * Dq);
        float4 a0 = xp0[0], b0 = xp0[1], a1 = xp1[0], b1 = xp1[1];
        rp[p][0] = (v2f){a0.x, a1.x}; rp[p][1] = (v2f){a0.y, a1.y};
        rp[p][2] = (v2f){a0.z, a1.z}; rp[p][3] = (v2f){a0.w, a1.w};
        rp[p][4] = (v2f){b0.x, b1.x}; rp[p][5] = (v2f){b0.y, b1.y};
        rp[p][6] = (v2f){b0.z, b1.z}; rp[p][7] = (v2f){b0.w, b1.w};
    }

    // qsum only for the owned token (j == slice)
    float qso[Dq];
#pragma unroll
    for (int d = 0; d < Dq; ++d) qso[d] = 0.0f;
    float lossacc = 0.0f;

    float* out_quant = out;                               // [B*T*D]
    float* out_loss  = out + (size_t)NTOK * Dq;           // [1]
    float* out_codes = out_loss + 1;                      // [Q*B*T] as float

    for (int q = 0; q < Qq; ++q) {
        // ---- stage codebook q into LDS, skewed by region (k>>8) ----
        {
            const float4* src = reinterpret_cast<const float4*>(
                codebooks + (size_t)q * Kq * Dq);
            float4* dst = reinterpret_cast<float4*>(s_cb);
#pragma unroll
            for (int it = 0; it < 8; ++it) {
                int i = tid + it * 256;
                dst[i + ((i >> 9) << 1)] = src[i];  // +2 float4 per 256-cw region
            }
        }
        __syncthreads();

        // ---- per-codeword squared norms (np order), skewed store ----
#pragma unroll
        for (int it = 0; it < 4; ++it) {
            int k = tid + it * 256;
            const float* c = s_cb + k * Dq + ((k >> 8) << 3);
            float n = __fmul_rn(c[0], c[0]);
#pragma unroll
            for (int d = 1; d < Dq; ++d)
                n = __fadd_rn(n, __fmul_rn(c[d], c[d]));
            s_cn[k + ((k >> 8) << 3)] = n;
        }
        __syncthreads();

        // ---- residual norms (np order), packed (same bits per component) ----
        v2f rnp[2];
#pragma unroll
        for (int p = 0; p < 2; ++p) {
            v2f n = rp[p][0] * rp[p][0];
#pragma unroll
            for (int d = 1; d < Dq; ++d)
                n = n + rp[p][d] * rp[p][d];
            rnp[p] = n;
        }

        // ---- argmin over this slice's 256 codewords, 4 tokens per read ----
        float best[4];
        int   bk[4];
#pragma unroll
        for (int j = 0; j < 4; ++j) { best[j] = __builtin_inff(); bk[j] = kbase; }

        const float4* cb4 = reinterpret_cast<const float4*>(s_cb)
                            + (size_t)kbase * 2 + slice * 2;
        const float*  cnp = s_cn + kbase + slice * 8;
#pragma unroll 2
        for (int k = 0; k < Kq / 4; ++k) {
            float4 ca = cb4[2 * k];
            float4 cc = cb4[2 * k + 1];
            float cn = cnp[k];
            int cand = kbase + k;
            v2f cnv = (v2f){cn, cn};
#pragma unroll
            for (int p = 0; p < 2; ++p) {
                v2f dot = rp[p][0] * (v2f){ca.x, ca.x};
                dot = __builtin_elementwise_fma(rp[p][1], (v2f){ca.y, ca.y}, dot);
                dot = __builtin_elementwise_fma(rp[p][2], (v2f){ca.z, ca.z}, dot);
                dot = __builtin_elementwise_fma(rp[p][3], (v2f){ca.w, ca.w}, dot);
                dot = __builtin_elementwise_fma(rp[p][4], (v2f){cc.x, cc.x}, dot);
                dot = __builtin_elementwise_fma(rp[p][5], (v2f){cc.y, cc.y}, dot);
                dot = __builtin_elementwise_fma(rp[p][6], (v2f){cc.z, cc.z}, dot);
                dot = __builtin_elementwise_fma(rp[p][7], (v2f){cc.w, cc.w}, dot);
                v2f d2 = __builtin_elementwise_fma(
                    dot, (v2f){-2.0f, -2.0f}, rnp[p] + cnv);
                float d20 = d2[0], d21 = d2[1];
                if (d20 < best[2*p])   { best[2*p]   = d20; bk[2*p]   = cand; }
                if (d21 < best[2*p+1]) { best[2*p+1] = d21; bk[2*p+1] = cand; }
            }
        }

        // ---- merge 4 slices: lexicographic (d2, k) min == np first-min ----
#pragma unroll
        for (int j = 0; j < 4; ++j) {
            float b = best[j]; int k = bk[j];
            {
                float ob = __shfl_xor(b, 16, 64);
                int   ok = __shfl_xor(k, 16, 64);
                if (ob < b || (ob == b && ok < k)) { b = ob; k = ok; }
            }
            {
                float ob = __shfl_xor(b, 32, 64);
                int   ok = __shfl_xor(k, 32, 64);
                if (ob < b || (ob == b && ok < k)) { b = ob; k = ok; }
            }
            best[j] = b; bk[j] = k;
        }

        const float sc = post_scale[q];
        const float bi = post_bias[q];

        // codes: lane writes its owned token (j == slice) -> fully coalesced
        out_codes[(size_t)q * NTOK + tbase + 16 * slice] = (float)bk[slice];

        // ---- update residuals (all 4 tokens); qsum/loss for owned only ----
#pragma unroll
        for (int j = 0; j < 4; ++j) {
            int kj = bk[j];
            const float* cc = s_cb + kj * Dq + ((kj >> 8) << 3);
            const int p = j >> 1, h = j & 1;
#pragma unroll
            for (int d = 0; d < Dq; ++d) {
                float e = cc[d];
                float rd = rp[p][d][h];
                float est = __fadd_rn(rd, __fsub_rn(e, rd));
                if (j == slice)
                    qso[d] = __fadd_rn(__fadd_rn(qso[d], __fmul_rn(est, sc)), bi);
                float nr = __fsub_rn(rd, e);
                float df = __fsub_rn(nr, e);
                if (j == slice) lossacc = fmaf(df, df, lossacc);
                rp[p][d][h] = nr;
            }
        }
        __syncthreads();   // before next q overwrites s_cb
    }

    // ---- 1x1 conv epilogue: owned token only -> coalesced wave store ----
    {
        float o[Dq];
#pragma unroll
        for (int e = 0; e < Dq; ++e) {
            float acc = __fmul_rn(qso[0], conv_w[e * Dq + 0]);
#pragma unroll
            for (int d = 1; d < Dq; ++d)
                acc = fmaf(qso[d], conv_w[e * Dq + d], acc);
            o[e] = __fadd_rn(acc, conv_b[e]);
        }
        float4* op = reinterpret_cast<float4*>(
            out_quant + (size_t)(tbase + 16 * slice) * Dq);
        op[0] = make_float4(o[0], o[1], o[2], o[3]);
        op[1] = make_float4(o[4], o[5], o[6], o[7]);
    }

    // ---- loss reduction: each token counted once (owner lane) ----
    float v = lossacc;
#pragma unroll
    for (int off = 32; off >= 1; off >>= 1)
        v += __shfl_xor(v, off, 64);
    if (lane == 0)
        atomicAdd(out_loss, v * LOSS_SCALE);
}

extern "C" void kernel_launch(void* const* d_in, const int* in_sizes, int n_in,
                              void* d_out, int out_size, void* d_ws, size_t ws_size,
                              hipStream_t stream) {
    const float* x     = (const float*)d_in[0];
    const float* cb    = (const float*)d_in[1];
    const float* ps    = (const float*)d_in[2];
    const float* pb    = (const float*)d_in[3];
    const float* cw    = (const float*)d_in[4];
    const float* cbias = (const float*)d_in[5];
    float* out = (float*)d_out;

    // zero the loss accumulator slot (d_out is poisoned before every call)
    hipMemsetAsync(out + (size_t)NTOK * Dq, 0, sizeof(float), stream);

    rvq_main<<<dim3(NTOK / 256), dim3(256), 0, stream>>>(
        x, cb, ps, pb, cw, cbias, out);
}